// Round 6
// baseline (138.648 us; speedup 1.0000x reference)
//
#include <hip/hip_runtime.h>
#include <hip/hip_bf16.h>

typedef _Float16 f16x8 __attribute__((ext_vector_type(8)));
typedef float f32x4 __attribute__((ext_vector_type(4)));

#define N_ROWS 4096
#define F_DIM 64
#define EMPF 0.1f
#define EMPD 0.1
#define ZEROV 9e-15f
#define WINDOW 2e-4f
#define REG_CAP 256u       // per-WAVE flagged slots; E=15, Poisson tail @256 ~ 0
#define N_REGIONS 4096     // 512 blocks * 8 waves

// ---------------- Kernel 1: xw = x*w, normalize, split fp32 -> f16 hi/lo ----
__global__ __launch_bounds__(256) void normalize_split_kernel(
    const float* __restrict__ x, const float* __restrict__ w,
    _Float16* __restrict__ hi, _Float16* __restrict__ lo) {
  const int lane = threadIdx.x & 63;
  const int wid = threadIdx.x >> 6;
  const int rg = blockIdx.x * 4 + wid;          // global row 0..16383 (b*4096+n)
  const int n = rg & (N_ROWS - 1);
  const float xv = x[rg * F_DIM + lane];
  const float wv = w[n * F_DIM + lane];
  const float p = xv * wv;
  float s = p * p;
#pragma unroll
  for (int off = 32; off >= 1; off >>= 1) s += __shfl_xor(s, off, 64);
  const float nrm = fmaxf(sqrtf(s), 1e-8f);
  const float xn = p / nrm;
  const _Float16 h = (_Float16)xn;
  const float rem = xn - (float)h;
  hi[rg * F_DIM + lane] = h;
  lo[rg * F_DIM + lane] = (_Float16)rem;
}

// ---------------- Kernel 2: row-streaming MFMA Gram ------------------------
// R6 structural change: block = 32 output ROWS x ALL 4096 cols (512 thr,
// 8 waves; wave wid streams cols [wid*512, wid*512+512) over 32 j-steps).
// Each wave writes 2KB CONTIGUOUS per output row (full DRAM pages) and the
// HBM channel-select bits (addr bits 8-13, col-derived) sweep completely.
// Old 128x128 tiles wrote 512B/row at 16KB stride -> ~35% DRAM write
// efficiency (R2-R5 stuck at ~115us gram regardless of store instr shape).
// cos = hi*hi + hi*lo + lo*hi (lo*lo ~ 2^-24 dropped); transposed mfma
// operand order (R2) -> 4 C-regs on col axis -> one f32x4 store per frag.
__global__ __launch_bounds__(512, 4) void gram_kernel(
    const _Float16* __restrict__ hi, const _Float16* __restrict__ lo,
    float* __restrict__ out, unsigned* __restrict__ cnt,
    unsigned* __restrict__ regions) {
  __shared__ unsigned lds_cnt[8];
  const int lane = threadIdx.x & 63;
  const int wid = threadIdx.x >> 6;
  if (lane == 0) lds_cnt[wid] = 0;   // per-wave counter; wave-order guarantees init-first

  const int b = blockIdx.y;
  const int row0 = blockIdx.x * 32;
  const int rbase = b * N_ROWS;
  const unsigned rgn = (((unsigned)b * gridDim.x + blockIdx.x) << 3) | (unsigned)wid;
  unsigned* __restrict__ region = regions + (size_t)rgn * REG_CAP;

  const int lr = lane & 15;         // fragment row
  const int lk = (lane >> 4) * 8;   // fragment k offset

  // a-side: 2 row-groups x 2 k-halves, hoisted for the whole col sweep.
  f16x8 ah[2][2], al[2][2];
#pragma unroll
  for (int g = 0; g < 2; ++g)
#pragma unroll
    for (int kf = 0; kf < 2; ++kf) {
      const int ra = (rbase + row0 + g * 16 + lr) * F_DIM + kf * 32 + lk;
      ah[g][kf] = *(const f16x8*)(hi + ra);
      al[g][kf] = *(const f16x8*)(lo + ra);
    }

  const int r_in = lane & 15;        // C/D (transposed): row within frag
  const int cb = (lane >> 4) * 4;    // col base within frag
  const int colbase = wid * 512;

  // b-side double buffer with 1-step prefetch.
  int rb = (rbase + colbase + lr) * F_DIM + lk;
  f16x8 bh0 = *(const f16x8*)(hi + rb);
  f16x8 bl0 = *(const f16x8*)(lo + rb);
  f16x8 bh1 = *(const f16x8*)(hi + rb + 32);
  f16x8 bl1 = *(const f16x8*)(lo + rb + 32);

#pragma unroll 1
  for (int j = 0; j < 32; ++j) {
    const int rbn = rb + (j < 31 ? 16 * F_DIM : 0);   // clamp: last prefetch re-reads
    f16x8 nbh0 = *(const f16x8*)(hi + rbn);
    f16x8 nbl0 = *(const f16x8*)(lo + rbn);
    f16x8 nbh1 = *(const f16x8*)(hi + rbn + 32);
    f16x8 nbl1 = *(const f16x8*)(lo + rbn + 32);

    f32x4 acc[2] = {};
#pragma unroll
    for (int g = 0; g < 2; ++g) {
      acc[g] = __builtin_amdgcn_mfma_f32_16x16x32_f16(bh0, ah[g][0], acc[g], 0, 0, 0);
      acc[g] = __builtin_amdgcn_mfma_f32_16x16x32_f16(bh0, al[g][0], acc[g], 0, 0, 0);
      acc[g] = __builtin_amdgcn_mfma_f32_16x16x32_f16(bl0, ah[g][0], acc[g], 0, 0, 0);
      acc[g] = __builtin_amdgcn_mfma_f32_16x16x32_f16(bh1, ah[g][1], acc[g], 0, 0, 0);
      acc[g] = __builtin_amdgcn_mfma_f32_16x16x32_f16(bh1, al[g][1], acc[g], 0, 0, 0);
      acc[g] = __builtin_amdgcn_mfma_f32_16x16x32_f16(bl1, ah[g][1], acc[g], 0, 0, 0);
    }

    const int col = colbase + j * 16 + cb;
#pragma unroll
    for (int g = 0; g < 2; ++g) {
      f32x4 v = acc[g];
      const int row = row0 + g * 16 + r_in;
      const bool near = fabsf(v[0] - EMPF) < WINDOW || fabsf(v[1] - EMPF) < WINDOW ||
                        fabsf(v[2] - EMPF) < WINDOW || fabsf(v[3] - EMPF) < WINDOW;
      if (__builtin_expect(__any((int)near), 0)) {
#pragma unroll
        for (int r = 0; r < 4; ++r) {
          if (fabsf(v[r] - EMPF) < WINDOW) {
            const unsigned pos = atomicAdd(&lds_cnt[wid], 1u);
            if (pos < REG_CAP)
              region[pos] = ((unsigned)b << 24) | ((unsigned)row << 12) | (unsigned)(col + r);
          }
        }
      }
#pragma unroll
      for (int r = 0; r < 4; ++r) v[r] = (v[r] > EMPF) ? v[r] : ZEROV;
      const size_t oi = ((size_t)b << 24) + ((size_t)row << 12) + (size_t)col;
      *(f32x4*)(out + oi) = v;   // plain store: L2 aggregates full lines
    }

    bh0 = nbh0; bl0 = nbl0; bh1 = nbh1; bl1 = nbl1;
    rb += 16 * F_DIM;
  }

  if (lane == 0) {
    const unsigned c = lds_cnt[wid];
    cnt[rgn] = c < REG_CAP ? c : REG_CAP;
  }
}

// ---------------- Kernel 3: fp64 exact recompute of near-threshold elems ----
// One wave per region (4096 regions, ~15 entries each).
__global__ __launch_bounds__(256) void refine_kernel(
    const float* __restrict__ x, const float* __restrict__ w,
    float* __restrict__ out, const unsigned* __restrict__ cnt,
    const unsigned* __restrict__ regions) {
  const int lane = threadIdx.x & 63;
  const unsigned wg0 = blockIdx.x * (blockDim.x >> 6) + (threadIdx.x >> 6);
  const unsigned nw = gridDim.x * (blockDim.x >> 6);
  for (unsigned rgn = wg0; rgn < N_REGIONS; rgn += nw) {
    const unsigned count = cnt[rgn];
    const unsigned* __restrict__ region = regions + (size_t)rgn * REG_CAP;
    for (unsigned e = 0; e < count; ++e) {
      const unsigned ent = region[e];
      const int b = (int)(ent >> 24);
      const int i = (int)((ent >> 12) & 4095);
      const int j = (int)(ent & 4095);
      const double wi = (double)w[i * F_DIM + lane];
      const double wj = (double)w[j * F_DIM + lane];
      const double xi = (double)x[(b * N_ROWS + i) * F_DIM + lane];
      const double xj = (double)x[(b * N_ROWS + j) * F_DIM + lane];
      const double pi = xi * wi;
      const double pj = xj * wj;
      double si = pi * pi, sj = pj * pj, sij = pi * pj;
#pragma unroll
      for (int off = 32; off >= 1; off >>= 1) {
        si += __shfl_xor(si, off, 64);
        sj += __shfl_xor(sj, off, 64);
        sij += __shfl_xor(sij, off, 64);
      }
      if (lane == 0) {
        const double ni = fmax(sqrt(si), 1e-8);
        const double nj = fmax(sqrt(sj), 1e-8);
        const double c = sij / (ni * nj);
        const double res = (c > EMPD) ? c : (double)ZEROV;
        out[((size_t)b << 24) + ((size_t)i << 12) + (size_t)j] = (float)res;
      }
    }
  }
}

extern "C" void kernel_launch(void* const* d_in, const int* in_sizes, int n_in,
                              void* d_out, int out_size, void* d_ws, size_t ws_size,
                              hipStream_t stream) {
  const float* x = (const float*)d_in[0];
  const float* w = (const float*)d_in[1];
  float* out = (float*)d_out;

  char* ws = (char*)d_ws;
  _Float16* hi = (_Float16*)ws;                                    // 2 MB
  _Float16* lo = (_Float16*)(ws + (size_t)16384 * 64 * 2);         // 2 MB
  unsigned* cnt = (unsigned*)(ws + (size_t)4 * 1024 * 1024);       // 16 KB
  unsigned* regions = (unsigned*)(ws + (size_t)4 * 1024 * 1024 + 16384); // 4 MB

  normalize_split_kernel<<<4096, 256, 0, stream>>>(x, w, hi, lo);
  gram_kernel<<<dim3(128, 4), 512, 0, stream>>>(hi, lo, out, cnt, regions);
  refine_kernel<<<1024, 256, 0, stream>>>(x, w, out, cnt, regions);
}